// Round 8
// baseline (40.716 us; speedup 1.0000x reference)
//
#include <hip/hip_runtime.h>

// x (256,160,160) f32 -> out (256,320,640) f32
#define CH  256
#define H_  160
#define W0_ 160
#define RH  160
#define RW  320
#define OH  320
#define OW  640

#define TKR 8               // res rows per block
#define TKC 320             // res cols per block (full width)
#define NBY 20              // 160/8
#define NWG (NBY * CH)              // 5120
#define NXCD 8
#define CPX (NWG / NXCD)            // 640 = 32 whole channels per XCD
// x tile: rows k0-2..k0+9 (12), cols -1..160 clamped (162); stride 164 words
#define XT_H 12
#define XT_W 162
#define XT_S 164

typedef float f4 __attribute__((ext_vector_type(4)));

__global__ __launch_bounds__(256)
void upsample_tsd_conv_kernel(const float* __restrict__ x, float* __restrict__ out) {
    __shared__ float xs[XT_H][XT_S];

    // XCD-chunk swizzle (bijective, NWG % 8 == 0): XCD k owns orig [640k,640k+640)
    // = 32 complete channels -> each x-slab lives in ONE L2; output sequential.
    const int bid  = blockIdx.x;
    const int orig = (bid & (NXCD - 1)) * CPX + (bid >> 3);
    const int c    = orig / NBY;
    const int by   = orig - c * NBY;

    const int k0 = by * TKR;
    const float* __restrict__ xc = x + (size_t)c * (H_ * W0_);
    const int tid = threadIdx.x;

    // ---- Phase 1: stage raw x rows k0-2..k0+9, cols -1..160 (clamped) ----
    #pragma unroll
    for (int it = 0; it < 8; ++it) {
        int idx = tid + it * 256;
        if (idx < XT_H * XT_W) {
            int rr = idx / XT_W;
            int cc = idx - rr * XT_W;
            int gr = min(H_ - 1, max(0, k0 - 2 + rr));
            int gc = min(W0_ - 1, max(0, cc - 1));
            xs[rr][cc] = xc[gr * W0_ + gc];
        }
    }
    __syncthreads();

    float* __restrict__ outc = out + (size_t)c * (OH * OW);

    // ---- Phase 2: 5 col-pair patches per thread; wave-uniform row parity ----
    // wave0 rows {0,2}, wave1 {4,6}, wave2 {1,3}, wave3 {5,7}
    const int par   = tid >> 7;                                // wave-uniform
    const int kr    = ((tid >> 6) & 1) * 4 + ((tid >> 5) & 1) * 2 + par;
    const int lane5 = tid & 31;
    const int k     = k0 + kr;
    const int oy    = 2 * k;

    for (int pp = 0; pp < 5; ++pp) {
        const int cp = lane5 + 32 * pp;    // col-pair: res cols 2cp, 2cp+1
        const int ml = cp + 1;             // LDS col of x col cp
        const int jc = cp << 1;

        float rt0[4], rt1[4], rt2[4];      // res rows k-1, k, k+1 x cols jc-1..jc+2

        if (par == 0) {   // k even: rows k+-1 odd (data at odd cols), row k even
            float X01 = xs[kr    ][ml],     X02 = xs[kr    ][ml + 1];
            float X10 = xs[kr + 1][ml - 1], X11 = xs[kr + 1][ml], X12 = xs[kr + 1][ml + 1];
            float X20 = xs[kr + 2][ml - 1], X21 = xs[kr + 2][ml], X22 = xs[kr + 2][ml + 1];
            float X30 = xs[kr + 3][ml - 1], X31 = xs[kr + 3][ml], X32 = xs[kr + 3][ml + 1];
            float X41 = xs[kr + 4][ml],     X42 = xs[kr + 4][ml + 1];
            rt0[0] = X10;
            rt0[1] = 0.25f * (X01 + X21 + X10 + X11);
            rt0[2] = X11;
            rt0[3] = 0.25f * (X02 + X22 + X11 + X12);
            rt1[0] = 0.25f * (X10 + X30 + X20 + X21);
            rt1[1] = X21;
            rt1[2] = 0.25f * (X11 + X31 + X21 + X22);
            rt1[3] = X22;
            rt2[0] = X30;
            rt2[1] = 0.25f * (X21 + X41 + X30 + X31);
            rt2[2] = X31;
            rt2[3] = 0.25f * (X22 + X42 + X31 + X32);
            if (by == 0 && kr == 0) {              // k==0: row-0 holes row-reflect
                rt1[0] = 0.25f * (2.f * X30 + X20 + X21);
                rt1[2] = 0.25f * (2.f * X31 + X21 + X22);
            }
            if (by == NBY - 1 && kr == TKR - 2) {  // row 159 holes (even cols) zero
                rt2[1] = 0.f; rt2[3] = 0.f;
            }
            if (cp == 0) {                         // res col -1 -> col 0
                rt0[0] = 0.25f * (X01 + X21 + 2.f * X11);
                rt1[0] = X21;
                rt2[0] = (by == NBY - 1 && kr == TKR - 2) ? 0.f
                         : 0.25f * (X21 + X41 + 2.f * X31);
            }
            if (cp == 159) {                       // jc==318: col 319 + col 320->319
                rt1[2] = 0.f;
                rt0[3] = X11;
                rt1[3] = 0.f;
                rt2[3] = X31;
            }
            if (by == 0 && kr == 0) {              // res row -1 -> row 0
                rt0[0] = rt1[0]; rt0[1] = rt1[1]; rt0[2] = rt1[2]; rt0[3] = rt1[3];
            }
        } else {          // k odd: rows k+-1 even (data at even cols), row k odd
            float X00 = xs[kr    ][ml - 1], X01 = xs[kr    ][ml];
            float X10 = xs[kr + 1][ml - 1], X11 = xs[kr + 1][ml], X12 = xs[kr + 1][ml + 1];
            float X20 = xs[kr + 2][ml - 1], X21 = xs[kr + 2][ml], X22 = xs[kr + 2][ml + 1];
            float X30 = xs[kr + 3][ml - 1], X31 = xs[kr + 3][ml], X32 = xs[kr + 3][ml + 1];
            float X40 = xs[kr + 4][ml - 1], X41 = xs[kr + 4][ml];
            rt0[0] = 0.25f * (X00 + X20 + X10 + X11);
            rt0[1] = X11;
            rt0[2] = 0.25f * (X01 + X21 + X11 + X12);
            rt0[3] = X12;
            rt1[0] = X20;
            rt1[1] = 0.25f * (X11 + X31 + X20 + X21);
            rt1[2] = X21;
            rt1[3] = 0.25f * (X12 + X32 + X21 + X22);
            rt2[0] = 0.25f * (X20 + X40 + X30 + X31);
            rt2[1] = X31;
            rt2[2] = 0.25f * (X21 + X41 + X31 + X32);
            rt2[3] = X32;
            if (by == 0 && kr == 1) {              // k==1: row 0 holes row-reflect
                rt0[0] = 0.25f * (2.f * X20 + X10 + X11);
                rt0[2] = 0.25f * (2.f * X21 + X11 + X12);
            }
            if (by == NBY - 1 && kr == TKR - 1) {  // k==159: own-row holes zero
                rt1[1] = 0.f; rt1[3] = 0.f;
            }
            if (cp == 0) {                         // res col -1 -> col 0
                rt0[0] = X11;
                rt1[0] = (by == NBY - 1 && kr == TKR - 1) ? 0.f
                         : 0.25f * (X11 + X31 + 2.f * X21);
                rt2[0] = X31;
            }
            if (cp == 159) {                       // jc==318
                rt0[2] = 0.f; rt2[2] = 0.f;
                rt0[3] = 0.f;
                rt1[3] = X21;
                rt2[3] = 0.f;
            }
            if (by == NBY - 1 && kr == TKR - 1) {  // res row 160 -> 159
                rt2[0] = rt1[0]; rt2[1] = rt1[1]; rt2[2] = rt1[2]; rt2[3] = rt1[3];
            }
        }

        // vertical blends: out 2k <- (k-1,k) w (.25,.75); 2k+1 <- (k,k+1) w (.75,.25)
        float v00 = 0.25f * rt0[0] + 0.75f * rt1[0];
        float v01 = 0.25f * rt0[1] + 0.75f * rt1[1];
        float v02 = 0.25f * rt0[2] + 0.75f * rt1[2];
        float v03 = 0.25f * rt0[3] + 0.75f * rt1[3];
        float v10 = 0.75f * rt1[0] + 0.25f * rt2[0];
        float v11 = 0.75f * rt1[1] + 0.25f * rt2[1];
        float v12 = 0.75f * rt1[2] + 0.25f * rt2[2];
        float v13 = 0.75f * rt1[3] + 0.25f * rt2[3];
        // horizontal blends -> pre-flip cols 2jc..2jc+3
        float p0 = 0.25f * v00 + 0.75f * v01;
        float p1 = 0.75f * v01 + 0.25f * v02;
        float p2 = 0.25f * v01 + 0.75f * v02;
        float p3 = 0.75f * v02 + 0.25f * v03;
        float q0 = 0.25f * v10 + 0.75f * v11;
        float q1 = 0.75f * v11 + 0.25f * v12;
        float q2 = 0.25f * v11 + 0.75f * v12;
        float q3 = 0.75f * v12 + 0.25f * v13;

        const int oxf = OW - 4 - 2 * jc;   // flipped base; half-wave = 512B contig
        *reinterpret_cast<f4*>(&outc[(size_t)oy       * OW + oxf]) = f4{p3, p2, p1, p0};
        *reinterpret_cast<f4*>(&outc[(size_t)(oy + 1) * OW + oxf]) = f4{q3, q2, q1, q0};
    }
}

extern "C" void kernel_launch(void* const* d_in, const int* in_sizes, int n_in,
                              void* d_out, int out_size, void* d_ws, size_t ws_size,
                              hipStream_t stream) {
    (void)in_sizes; (void)n_in; (void)d_ws; (void)ws_size; (void)out_size;
    const float* x = (const float*)d_in[0];
    float* out = (float*)d_out;
    dim3 grid(NWG);            // 5120 blocks, 1D, XCD-chunk swizzled in-kernel
    dim3 block(256);
    upsample_tsd_conv_kernel<<<grid, block, 0, stream>>>(x, out);
}

// Round 9
// 39.463 us; speedup vs baseline: 1.0318x; 1.0318x over previous
//
#include <hip/hip_runtime.h>

// x (256,160,160) f32 -> out (256,320,640) f32
#define CH  256
#define H_  160
#define W0_ 160
#define RH  160
#define RW  320
#define OH  320
#define OW  640

#define TKR 8               // res rows per block
#define TKC 64              // res cols per block
#define NBX 5               // 320/64
#define NBY 20              // 160/8
#define NWG (NBX * NBY * CH)        // 25600
#define NXCD 8
#define CPX (NWG / NXCD)            // 3200 blocks per XCD chunk
// x tile: rows k0-2..k0+9 (12), cols m0-1..m0+32 (34); stride 36 words
#define XT_H 12
#define XT_W 34
#define XT_S 36

typedef float f4 __attribute__((ext_vector_type(4)));

__global__ __launch_bounds__(256)
void upsample_tsd_conv_kernel(const float* __restrict__ x, float* __restrict__ out) {
    __shared__ float xs[XT_H][XT_S];

    // XCD-chunk swizzle (bijective, NWG % 8 == 0): XCD k owns original blocks
    // [k*3200,(k+1)*3200) = 32 complete channels -> each x-slab lives in ONE L2.
    const int bid  = blockIdx.x;
    const int orig = (bid & (NXCD - 1)) * CPX + (bid >> 3);
    const int c    = orig / (NBX * NBY);        // channel-major
    const int tsub = orig - c * (NBX * NBY);
    const int by   = tsub / NBX;
    const int bx   = tsub - by * NBX;

    const int k0 = by * TKR;
    const int j0 = bx * TKC;
    const int m0 = j0 >> 1;
    const float* __restrict__ xc = x + (size_t)c * (H_ * W0_);
    const int tid = threadIdx.x;

    // ---- Phase 1: stage raw x tile (index-clamped), 408 elems, <=2 loads ----
    #pragma unroll
    for (int it = 0; it < 2; ++it) {
        int idx = tid + it * 256;
        if (idx < XT_H * XT_W) {
            int rr = idx / XT_W;
            int cc = idx - rr * XT_W;
            int gr = min(H_ - 1, max(0, k0 - 2 + rr));
            int gc = min(W0_ - 1, max(0, m0 - 1 + cc));
            xs[rr][cc] = xc[gr * W0_ + gc];
        }
    }
    __syncthreads();

    float* __restrict__ outc = out + (size_t)c * (OH * OW);

    // ---- Phase 2: one 3x4 res patch -> 2x4 outputs per thread ----
    // Wave-uniform parity: wave0 rows {0,2}, wave1 {4,6}, wave2 {1,3}, wave3 {5,7}
    const int par = tid >> 7;                                  // wave-uniform
    const int kr  = ((tid >> 6) & 1) * 4 + ((tid >> 5) & 1) * 2 + par;
    const int cp  = tid & 31;          // col-pair index: res cols 2cp, 2cp+1
    const int ml  = cp + 1;            // LDS col of x col m0+cp
    const int k   = k0 + kr;
    const int jc  = j0 + (cp << 1);

    float rt0[4], rt1[4], rt2[4];      // res rows k-1, k, k+1 x cols jc-1..jc+2

    if (par == 0) {   // k even: rows k+-1 odd (data at odd cols), row k even
        float X01 = xs[kr    ][ml],     X02 = xs[kr    ][ml + 1];
        float X10 = xs[kr + 1][ml - 1], X11 = xs[kr + 1][ml], X12 = xs[kr + 1][ml + 1];
        float X20 = xs[kr + 2][ml - 1], X21 = xs[kr + 2][ml], X22 = xs[kr + 2][ml + 1];
        float X30 = xs[kr + 3][ml - 1], X31 = xs[kr + 3][ml], X32 = xs[kr + 3][ml + 1];
        float X41 = xs[kr + 4][ml],     X42 = xs[kr + 4][ml + 1];
        rt0[0] = X10;
        rt0[1] = 0.25f * (X01 + X21 + X10 + X11);
        rt0[2] = X11;
        rt0[3] = 0.25f * (X02 + X22 + X11 + X12);
        rt1[0] = 0.25f * (X10 + X30 + X20 + X21);
        rt1[1] = X21;
        rt1[2] = 0.25f * (X11 + X31 + X21 + X22);
        rt1[3] = X22;
        rt2[0] = X30;
        rt2[1] = 0.25f * (X21 + X41 + X30 + X31);
        rt2[2] = X31;
        rt2[3] = 0.25f * (X22 + X42 + X31 + X32);
        if (by == 0 && kr == 0) {              // k==0: row-0 holes row-reflect
            rt1[0] = 0.25f * (2.f * X30 + X20 + X21);
            rt1[2] = 0.25f * (2.f * X31 + X21 + X22);
        }
        if (by == NBY - 1 && kr == TKR - 2) {  // row 159 holes (even cols) zero
            rt2[1] = 0.f; rt2[3] = 0.f;
        }
        if (bx == 0 && cp == 0) {              // res col -1 -> col 0
            rt0[0] = 0.25f * (X01 + X21 + 2.f * X11);
            rt1[0] = X21;
            rt2[0] = (by == NBY - 1 && kr == TKR - 2) ? 0.f
                     : 0.25f * (X21 + X41 + 2.f * X31);
        }
        if (bx == NBX - 1 && cp == 31) {       // jc==318: col 319 + col 320->319
            rt1[2] = 0.f;
            rt0[3] = X11;
            rt1[3] = 0.f;
            rt2[3] = X31;
        }
        if (by == 0 && kr == 0) {              // res row -1 -> row 0
            rt0[0] = rt1[0]; rt0[1] = rt1[1]; rt0[2] = rt1[2]; rt0[3] = rt1[3];
        }
    } else {          // k odd: rows k+-1 even (data at even cols), row k odd
        float X00 = xs[kr    ][ml - 1], X01 = xs[kr    ][ml];
        float X10 = xs[kr + 1][ml - 1], X11 = xs[kr + 1][ml], X12 = xs[kr + 1][ml + 1];
        float X20 = xs[kr + 2][ml - 1], X21 = xs[kr + 2][ml], X22 = xs[kr + 2][ml + 1];
        float X30 = xs[kr + 3][ml - 1], X31 = xs[kr + 3][ml], X32 = xs[kr + 3][ml + 1];
        float X40 = xs[kr + 4][ml - 1], X41 = xs[kr + 4][ml];
        rt0[0] = 0.25f * (X00 + X20 + X10 + X11);
        rt0[1] = X11;
        rt0[2] = 0.25f * (X01 + X21 + X11 + X12);
        rt0[3] = X12;
        rt1[0] = X20;
        rt1[1] = 0.25f * (X11 + X31 + X20 + X21);
        rt1[2] = X21;
        rt1[3] = 0.25f * (X12 + X32 + X21 + X22);
        rt2[0] = 0.25f * (X20 + X40 + X30 + X31);
        rt2[1] = X31;
        rt2[2] = 0.25f * (X21 + X41 + X31 + X32);
        rt2[3] = X32;
        if (by == 0 && kr == 1) {              // k==1: row 0 holes row-reflect
            rt0[0] = 0.25f * (2.f * X20 + X10 + X11);
            rt0[2] = 0.25f * (2.f * X21 + X11 + X12);
        }
        if (by == NBY - 1 && kr == TKR - 1) {  // k==159: own-row holes zero
            rt1[1] = 0.f; rt1[3] = 0.f;
        }
        if (bx == 0 && cp == 0) {              // res col -1 -> col 0
            rt0[0] = X11;
            rt1[0] = (by == NBY - 1 && kr == TKR - 1) ? 0.f
                     : 0.25f * (X11 + X31 + 2.f * X21);
            rt2[0] = X31;
        }
        if (bx == NBX - 1 && cp == 31) {       // jc==318
            rt0[2] = 0.f; rt2[2] = 0.f;
            rt0[3] = 0.f;
            rt1[3] = X21;
            rt2[3] = 0.f;
        }
        if (by == NBY - 1 && kr == TKR - 1) {  // res row 160 -> 159
            rt2[0] = rt1[0]; rt2[1] = rt1[1]; rt2[2] = rt1[2]; rt2[3] = rt1[3];
        }
    }

    // vertical blends: out row 2k <- (k-1,k) w (.25,.75); 2k+1 <- (k,k+1) w (.75,.25)
    float v00 = 0.25f * rt0[0] + 0.75f * rt1[0];
    float v01 = 0.25f * rt0[1] + 0.75f * rt1[1];
    float v02 = 0.25f * rt0[2] + 0.75f * rt1[2];
    float v03 = 0.25f * rt0[3] + 0.75f * rt1[3];
    float v10 = 0.75f * rt1[0] + 0.25f * rt2[0];
    float v11 = 0.75f * rt1[1] + 0.25f * rt2[1];
    float v12 = 0.75f * rt1[2] + 0.25f * rt2[2];
    float v13 = 0.75f * rt1[3] + 0.25f * rt2[3];
    // horizontal blends -> pre-flip cols 2jc..2jc+3
    float p0 = 0.25f * v00 + 0.75f * v01;
    float p1 = 0.75f * v01 + 0.25f * v02;
    float p2 = 0.25f * v01 + 0.75f * v02;
    float p3 = 0.75f * v02 + 0.25f * v03;
    float q0 = 0.25f * v10 + 0.75f * v11;
    float q1 = 0.75f * v11 + 0.25f * v12;
    float q2 = 0.25f * v11 + 0.75f * v12;
    float q3 = 0.75f * v12 + 0.25f * v13;

    const int oy  = 2 * k;
    const int oxf = OW - 4 - 2 * jc;   // flipped base col; half-wave = 512B contig
    *reinterpret_cast<f4*>(&outc[(size_t)oy       * OW + oxf]) = f4{p3, p2, p1, p0};
    *reinterpret_cast<f4*>(&outc[(size_t)(oy + 1) * OW + oxf]) = f4{q3, q2, q1, q0};
}

extern "C" void kernel_launch(void* const* d_in, const int* in_sizes, int n_in,
                              void* d_out, int out_size, void* d_ws, size_t ws_size,
                              hipStream_t stream) {
    (void)in_sizes; (void)n_in; (void)d_ws; (void)ws_size; (void)out_size;
    const float* x = (const float*)d_in[0];
    float* out = (float*)d_out;
    dim3 grid(NWG);            // 25600 blocks, 1D, XCD-chunk swizzled in-kernel
    dim3 block(256);
    upsample_tsd_conv_kernel<<<grid, block, 0, stream>>>(x, out);
}